// Round 7
// baseline (30.674 us; speedup 1.0000x reference)
//
#include <hip/hip_runtime.h>
#include <math.h>

#define TT   256
#define TM1  255
#define QD   9
#define KD   5
#define NH   3
#define DD   15   // NH*KD
#define HID  75   // 5*DD
#define NR   18   // NH + DD reduce values

#define K2E  2.8853900817779268f   // 2*log2(e)
#define L2E  1.4426950408889634f   // log2(e)
#define INVK 0.34657359027997264f  // ln(2)/2 = 1/K2E

__device__ __forceinline__ float fast_rcp(float x) {
    return __builtin_amdgcn_rcpf(x);   // v_rcp_f32
}

__device__ __forceinline__ float exp2_raw(float x) {   // v_exp_f32: 2^x
    float r; asm("v_exp_f32 %0, %1" : "=v"(r) : "v"(x)); return r;
}

template<int CTRL>
__device__ __forceinline__ float dpp_add(float x) {
    int y = __builtin_amdgcn_update_dpp(0, __float_as_int(x), CTRL, 0xf, 0xf, true);
    return x + __int_as_float(y);
}

// full-rate VALU wave64 sum; result valid in lane 63
__device__ __forceinline__ float wave_sum63(float x) {
    x = dpp_add<0x111>(x);  // row_shr:1
    x = dpp_add<0x112>(x);  // row_shr:2
    x = dpp_add<0x114>(x);  // row_shr:4
    x = dpp_add<0x118>(x);  // row_shr:8
    x = dpp_add<0x142>(x);  // row_bcast:15
    x = dpp_add<0x143>(x);  // row_bcast:31
    return x;
}

__device__ __forceinline__ float bcast(float x, int l) {
    return __int_as_float(__builtin_amdgcn_readlane(__float_as_int(x), l));
}

__global__ __launch_bounds__(256, 8)   // pin 8 waves/EU -> VGPR<=64, one residency round
void fused_block_kernel(const float* __restrict__ state,   // (32,256,7)
                        const float* __restrict__ action,  // (32,256,2)
                        const float* __restrict__ Wk,      // (15,5)
                        const float* __restrict__ Wq,      // (15,9)
                        const float* __restrict__ Wv,      // (15,5)
                        const float* __restrict__ att_bias,// (5)
                        const float* __restrict__ Wscore,  // (1,5)
                        const float* __restrict__ bscore,  // (1)
                        const float* __restrict__ g1,
                        const float* __restrict__ beta1,
                        const float* __restrict__ W1,      // (75,15)
                        const float* __restrict__ bff1,    // (75)
                        const float* __restrict__ W2,      // (15,75)
                        const float* __restrict__ bff2,    // (15)
                        const float* __restrict__ g2,
                        const float* __restrict__ beta2,
                        float* __restrict__ out)           // (32,256,15)
{
    const int tid  = threadIdx.x;
    const int lane = tid & 63;
    const int wv   = __builtin_amdgcn_readfirstlane(tid >> 6);  // SGPR wave id
    const int qgrp = blockIdx.x * 4 + wv;    // global query index (b*256+qi)
    const int b    = qgrp >> 8;              // same for all 4 waves of a block
    const int qi   = qgrp & 255;             // uniform per wave

    // SoA neighbor cache: stride-1 reads -> conflict-free LDS
    __shared__ float s_s0[TT], s_s1[TT], s_s2[TT], s_s3[TT], s_sn[TT], s_cs[TT];
    __shared__ float s_h[4][76];             // per-wave MLP hidden slice

    const float* __restrict__ sb = state + (size_t)b*TT*7;

    // ---- stage all 256 rows + per-j sincos ONCE per block (shared by 4 waves)
    {
        const float* sj = sb + tid*7;
        const float th = sj[6];
        s_s0[tid] = sj[0];
        s_s1[tid] = sj[1];
        s_s2[tid] = sj[2];
        s_s3[tid] = sj[3];
        // ref rotates by ang = pi/2 - theta_j: cos(ang)=sin(th), sin(ang)=cos(th)
        s_cs[tid] = __sinf(th);   // native
        s_sn[tid] = __cosf(th);   // native
    }

    // ---- query projection (+att_bias folded) lanes 0..14; scaled by 2*log2e
    const float* __restrict__ sti = sb + qi*7;   // uniform -> s_loads
    float qv = 0.0f;
    if (lane < DD) {
        float acc = att_bias[lane % KD];
        #pragma unroll
        for (int k = 0; k < 7; k++) acc = fmaf(Wq[lane*QD+k], sti[k], acc);
        acc = fmaf(Wq[lane*QD+7], action[((size_t)b*TT+qi)*2 + 0], acc);
        acc = fmaf(Wq[lane*QD+8], action[((size_t)b*TT+qi)*2 + 1], acc);
        qv = acc * K2E;
    }
    float qb2[DD];                            // SGPRs via readlane
    #pragma unroll
    for (int d = 0; d < DD; d++) qb2[d] = bcast(qv, d);

    // score constants in exp2 domain
    float w2[KD];
    float Cn = bscore[0];
    #pragma unroll
    for (int kk = 0; kk < KD; kk++) { float w = Wscore[kk]; w2[kk] = -K2E*w; Cn += w; }
    const float C2 = L2E * Cn;

    const float si0 = sti[0], si1 = sti[1], si2 = sti[2], si3 = sti[3];

    __syncthreads();

    // ---- per-pair phase: 4 neighbors per lane, fused, minimal live set
    float red[NR];
    #pragma unroll
    for (int n = 0; n < NR; n++) red[n] = 0.0f;

    #pragma unroll
    for (int pp = 0; pp < 4; pp++) {
        const int mm = lane + pp*64;
        int jj = mm + (mm >= qi ? 1 : 0);
        jj = (jj < TT) ? jj : (TT-1);                 // keep LDS reads in-bounds
        const float Cp = (mm < TM1) ? C2 : -100.0f;   // invalid pair -> p ~ 0

        const float d0 = s_s0[jj]-si0, d1 = s_s1[jj]-si1;
        const float d2 = s_s2[jj]-si2, d3 = s_s3[jj]-si3;
        const float cs = s_cs[jj],     sn = s_sn[jj];
        const float xr0 = d0*cs - d1*sn, yr0 = d0*sn + d1*cs;
        const float xr1 = d2*cs - d3*sn, yr1 = d2*sn + d3*cs;
        const float s2   = fmaxf(fmaf(xr0, xr0, yr0*yr0), 1e-12f); // NaN-proof
        const float rinv = __builtin_amdgcn_rsqf(s2);
        const float r    = s2 * rinv;
        // sigmoid(1-5(r-0.2)) = rcp(1 + exp2(5*log2e*r - 2*log2e))
        const float rt   = fast_rcp(1.0f + exp2_raw(fmaf(7.213475204444817f, r,
                                                         -2.8853900817779268f)));
        const float t  = K2E * rinv;
        const float f0 = t * xr0;
        const float f1 = t * yr0;
        const float f2 = K2E * xr1;
        const float f3 = K2E * yr1;
        const float f4 = K2E * rt;

        #pragma unroll
        for (int h = 0; h < NH; h++) {
            float sc = Cp;
            #pragma unroll
            for (int kk = 0; kk < KD; kk++) {
                const int d = h*KD + kk;
                float a = qb2[d];
                a = fmaf(Wk[d*KD+0], f0, a);
                a = fmaf(Wk[d*KD+1], f1, a);
                a = fmaf(Wk[d*KD+2], f2, a);
                a = fmaf(Wk[d*KD+3], f3, a);
                a = fmaf(Wk[d*KD+4], f4, a);
                // wsc*tanh(a_nat) = wsc - 2*wsc*rcp(exp2(a2)+1), folded into C2/w2
                sc = fmaf(w2[kk], fast_rcp(exp2_raw(a) + 1.0f), sc);
            }
            const float p = exp2_raw(sc);   // bounded |sc| -> no max-subtraction
            red[h] += p;
            red[NH+h*KD+0] = fmaf(p, f0, red[NH+h*KD+0]);
            red[NH+h*KD+1] = fmaf(p, f1, red[NH+h*KD+1]);
            red[NH+h*KD+2] = fmaf(p, f2, red[NH+h*KD+2]);
            red[NH+h*KD+3] = fmaf(p, f3, red[NH+h*KD+3]);
            red[NH+h*KD+4] = fmaf(p, f4, red[NH+h*KD+4]);
        }
    }

    // ---- single-wave reduction + broadcast of the 18 totals
    #pragma unroll
    for (int n = 0; n < NR; n++) red[n] = wave_sum63(red[n]);
    float fin[NR];
    #pragma unroll
    for (int n = 0; n < NR; n++) fin[n] = bcast(red[n], 63);

    // ---- Wv projection (deferred, linear) + softmax normalize (lanes 0..14)
    // fin's value part carries factor K2E -> un-scale by INVK
    float xm = 0.0f;
    if (lane < DD) {
        const int h = lane / KD;
        float acc = 0.0f;
        #pragma unroll
        for (int c = 0; c < KD; c++) acc = fmaf(Wv[lane*KD+c], fin[NH+h*KD+c], acc);
        xm = acc * fast_rcp(fin[h]) * INVK;
    }

    // ---- LN1 across lanes 0..15 (lane 15 contributes 0)
    float s1 = xm, sq = xm*xm;
    #pragma unroll
    for (int off = 8; off >= 1; off >>= 1) {
        s1 += __shfl_xor(s1, off, 16);
        sq += __shfl_xor(sq, off, 16);
    }
    const float mu1   = s1 * (1.0f/DD);
    const float rstd1 = rsqrtf(sq * (1.0f/DD) - mu1*mu1 + 1e-5f);
    float xln = 0.0f;
    if (lane < DD) xln = (xm - mu1) * rstd1 * g1[lane] + beta1[lane];

    // broadcast LN1 output for the MLP (SGPRs)
    float xs[DD];
    #pragma unroll
    for (int d = 0; d < DD; d++) xs[d] = bcast(xln, d);

    // ---- MLP layer 1: 75 hidden units over 64 lanes (lanes 0..10 do two)
    {
        float h0 = bff1[lane];
        #pragma unroll
        for (int k = 0; k < DD; k++) h0 = fmaf(W1[lane*DD+k], xs[k], h0);
        s_h[wv][lane] = fmaxf(h0, 0.0f);
        if (lane < HID-64) {
            float h1 = bff1[lane+64];
            #pragma unroll
            for (int k = 0; k < DD; k++) h1 = fmaf(W1[(lane+64)*DD+k], xs[k], h1);
            s_h[wv][lane+64] = fmaxf(h1, 0.0f);
        }
    }
    // same-wave LDS producer/consumer: compiler inserts lgkmcnt wait

    // ---- MLP layer 2: 3 chunks x 25 over lane groups, combine via shfl
    const int c2  = lane >> 4;               // 0..3
    const int d2c = lane & 15;
    const int cc  = (c2 < 3) ? c2 : 2;       // clamp for safe addressing
    const int dc  = (d2c < DD) ? d2c : 0;
    float acc2 = 0.0f;
    #pragma unroll
    for (int k = 0; k < 25; k++)
        acc2 = fmaf(W2[dc*HID + cc*25 + k], s_h[wv][cc*25 + k], acc2);
    acc2 = (c2 < 3) ? acc2 : 0.0f;           // kill duplicated chunk
    acc2 += __shfl_xor(acc2, 16);
    acc2 += __shfl_xor(acc2, 32);            // lanes 0..15 hold full sums

    // ---- residual + LN2 + store
    float x2 = 0.0f;
    if (lane < DD) x2 = xln + bff2[lane] + acc2;   // residual uses post-LN1 x
    float t1 = x2, t2 = x2*x2;
    #pragma unroll
    for (int off = 8; off >= 1; off >>= 1) {
        t1 += __shfl_xor(t1, off, 16);
        t2 += __shfl_xor(t2, off, 16);
    }
    const float mu2   = t1 * (1.0f/DD);
    const float rstd2 = rsqrtf(t2 * (1.0f/DD) - mu2*mu2 + 1e-5f);
    if (lane < DD)
        out[(size_t)qgrp*DD + lane] = (x2 - mu2) * rstd2 * g2[lane] + beta2[lane];
}

extern "C" void kernel_launch(void* const* d_in, const int* in_sizes, int n_in,
                              void* d_out, int out_size, void* d_ws, size_t ws_size,
                              hipStream_t stream) {
    const float* state    = (const float*)d_in[0];
    const float* action   = (const float*)d_in[1];
    const float* Wk       = (const float*)d_in[2];
    const float* Wq       = (const float*)d_in[3];
    const float* Wv       = (const float*)d_in[4];
    const float* att_bias = (const float*)d_in[5];
    const float* Wscore   = (const float*)d_in[6];
    const float* bscore   = (const float*)d_in[7];
    const float* g1       = (const float*)d_in[8];
    const float* beta1    = (const float*)d_in[9];
    const float* W1       = (const float*)d_in[10];
    const float* bff1     = (const float*)d_in[11];
    const float* W2       = (const float*)d_in[12];
    const float* bff2     = (const float*)d_in[13];
    const float* g2       = (const float*)d_in[14];
    const float* beta2    = (const float*)d_in[15];
    float* out = (float*)d_out;

    dim3 grid(32 * 256 / 4);   // 4 queries (waves) per block, 8 blocks/CU
    dim3 block(256);
    fused_block_kernel<<<grid, block, 0, stream>>>(
        state, action, Wk, Wq, Wv, att_bias, Wscore, bscore,
        g1, beta1, W1, bff1, W2, bff2, g2, beta2, out);
}

// Round 8
// 24.975 us; speedup vs baseline: 1.2282x; 1.2282x over previous
//
#include <hip/hip_runtime.h>
#include <math.h>

#define TT   256
#define TM1  255
#define QD   9
#define KD   5
#define NH   3
#define DD   15   // NH*KD
#define HID  75   // 5*DD
#define NR   18   // NH + DD reduce values

#define K2E  2.8853900817779268f   // 2*log2(e)
#define L2E  1.4426950408889634f   // log2(e)
#define INVK 0.34657359027997264f  // ln(2)/2 = 1/K2E

typedef float v2f __attribute__((ext_vector_type(2)));

__device__ __forceinline__ v2f v2splat(float s) { v2f r; r.x = s; r.y = s; return r; }

__device__ __forceinline__ float fast_rcp(float x) {
    return __builtin_amdgcn_rcpf(x);   // v_rcp_f32
}

__device__ __forceinline__ float exp2_raw(float x) {   // v_exp_f32: 2^x
    float r; asm("v_exp_f32 %0, %1" : "=v"(r) : "v"(x)); return r;
}

template<int CTRL>
__device__ __forceinline__ float dpp_add(float x) {
    int y = __builtin_amdgcn_update_dpp(0, __float_as_int(x), CTRL, 0xf, 0xf, true);
    return x + __int_as_float(y);
}

// full-rate VALU wave64 sum; result valid in lane 63
__device__ __forceinline__ float wave_sum63(float x) {
    x = dpp_add<0x111>(x);  // row_shr:1
    x = dpp_add<0x112>(x);  // row_shr:2
    x = dpp_add<0x114>(x);  // row_shr:4
    x = dpp_add<0x118>(x);  // row_shr:8
    x = dpp_add<0x142>(x);  // row_bcast:15
    x = dpp_add<0x143>(x);  // row_bcast:31
    return x;
}

__device__ __forceinline__ float bcast(float x, int l) {
    return __int_as_float(__builtin_amdgcn_readlane(__float_as_int(x), l));
}

__global__ __launch_bounds__(256)
void fused_block_kernel(const float* __restrict__ state,   // (32,256,7)
                        const float* __restrict__ action,  // (32,256,2)
                        const float* __restrict__ Wk,      // (15,5)
                        const float* __restrict__ Wq,      // (15,9)
                        const float* __restrict__ Wv,      // (15,5)
                        const float* __restrict__ att_bias,// (5)
                        const float* __restrict__ Wscore,  // (1,5)
                        const float* __restrict__ bscore,  // (1)
                        const float* __restrict__ g1,
                        const float* __restrict__ beta1,
                        const float* __restrict__ W1,      // (75,15)
                        const float* __restrict__ bff1,    // (75)
                        const float* __restrict__ W2,      // (15,75)
                        const float* __restrict__ bff2,    // (15)
                        const float* __restrict__ g2,
                        const float* __restrict__ beta2,
                        float* __restrict__ out)           // (32,256,15)
{
    const int tid  = threadIdx.x;
    const int lane = tid & 63;
    const int wv   = __builtin_amdgcn_readfirstlane(tid >> 6);  // SGPR wave id
    const int qgrp = blockIdx.x * 4 + wv;    // global query index (b*256+qi)
    const int b    = qgrp >> 8;
    const int qi   = qgrp & 255;             // uniform per wave

    __shared__ float s_h[4][76];             // per-wave MLP hidden slice

    const float* __restrict__ sb  = state + (size_t)b*TT*7;
    const float* __restrict__ sti = sb + qi*7;   // uniform -> s_loads
    const float si0 = sti[0], si1 = sti[1], si2 = sti[2], si3 = sti[3];

    // ---- query projection (+att_bias folded) lanes 0..14; scaled by 2*log2e
    float qv = 0.0f;
    if (lane < DD) {
        float acc = att_bias[lane % KD];
        #pragma unroll
        for (int k = 0; k < 7; k++) acc = fmaf(Wq[lane*QD+k], sti[k], acc);
        acc = fmaf(Wq[lane*QD+7], action[((size_t)b*TT+qi)*2 + 0], acc);
        acc = fmaf(Wq[lane*QD+8], action[((size_t)b*TT+qi)*2 + 1], acc);
        qv = acc * K2E;
    }
    float qb2[DD];
    #pragma unroll
    for (int d = 0; d < DD; d++) qb2[d] = bcast(qv, d);

    // score constants in exp2 domain
    float w2[KD];
    float Cn = bscore[0];
    #pragma unroll
    for (int kk = 0; kk < KD; kk++) { float w = Wscore[kk]; w2[kk] = -K2E*w; Cn += w; }
    const float C2 = L2E * Cn;

    // ---- per-pair phase: 2 float2 groups of 2 pairs -> v_pk_fma_f32 packing
    v2f rv[NR];
    #pragma unroll
    for (int n = 0; n < NR; n++) rv[n] = v2splat(0.0f);

    #pragma unroll
    for (int g = 0; g < 2; g++) {
        const int mm0 = lane + g*128;
        const int mm1 = mm0 + 64;
        const int jj0 = mm0 + (mm0 >= qi ? 1 : 0);       // always <= 255
        int       jj1 = mm1 + (mm1 >= qi ? 1 : 0);
        jj1 = (jj1 < TT) ? jj1 : (TT-1);                 // clamp (one lane, g=1)
        const float* __restrict__ r0 = sb + jj0*7;
        const float* __restrict__ r1 = sb + jj1*7;

        v2f d0, d1, d2, d3, th;
        d0.x = r0[0]; d0.y = r1[0];
        d1.x = r0[1]; d1.y = r1[1];
        d2.x = r0[2]; d2.y = r1[2];
        d3.x = r0[3]; d3.y = r1[3];
        th.x = r0[6]; th.y = r1[6];
        d0 = d0 - v2splat(si0);
        d1 = d1 - v2splat(si1);
        d2 = d2 - v2splat(si2);
        d3 = d3 - v2splat(si3);

        // ref rotates by ang = pi/2 - theta_j: cos(ang)=sin(th), sin(ang)=cos(th)
        v2f cs, sn;
        cs.x = __sinf(th.x); cs.y = __sinf(th.y);   // native v_sin
        sn.x = __cosf(th.x); sn.y = __cosf(th.y);   // native v_cos

        v2f xr0 = d0*cs - d1*sn;
        v2f yr0 = d0*sn + d1*cs;
        v2f xr1 = d2*cs - d3*sn;
        v2f yr1 = d2*sn + d3*cs;
        v2f s2  = xr0*xr0 + yr0*yr0;
        s2.x = fmaxf(s2.x, 1e-12f);                 // NaN-proof (self-pair clamp)
        s2.y = fmaxf(s2.y, 1e-12f);
        v2f rinv;
        rinv.x = __builtin_amdgcn_rsqf(s2.x);
        rinv.y = __builtin_amdgcn_rsqf(s2.y);
        v2f r = s2 * rinv;
        // sigmoid(1-5(r-0.2)) = rcp(1 + exp2(5*log2e*r - 2*log2e))
        v2f ea;
        ea.x = exp2_raw(fmaf(7.213475204444817f, r.x, -2.8853900817779268f));
        ea.y = exp2_raw(fmaf(7.213475204444817f, r.y, -2.8853900817779268f));
        v2f rt;
        rt.x = fast_rcp(1.0f + ea.x);
        rt.y = fast_rcp(1.0f + ea.y);

        v2f t  = v2splat(K2E) * rinv;
        v2f f0 = t * xr0;
        v2f f1 = t * yr0;
        v2f f2 = v2splat(K2E) * xr1;
        v2f f3 = v2splat(K2E) * yr1;
        v2f f4 = v2splat(K2E) * rt;

        v2f Cp;
        Cp.x = (mm0 < TM1) ? C2 : -100.0f;          // invalid pair -> p ~ 0
        Cp.y = (mm1 < TM1) ? C2 : -100.0f;

        #pragma unroll
        for (int h = 0; h < NH; h++) {
            v2f sc = Cp;
            #pragma unroll
            for (int kk = 0; kk < KD; kk++) {
                const int d = h*KD + kk;
                v2f a = v2splat(qb2[d]);
                a = a + v2splat(Wk[d*KD+0]) * f0;   // contracts to v_pk_fma_f32
                a = a + v2splat(Wk[d*KD+1]) * f1;
                a = a + v2splat(Wk[d*KD+2]) * f2;
                a = a + v2splat(Wk[d*KD+3]) * f3;
                a = a + v2splat(Wk[d*KD+4]) * f4;
                v2f e;
                e.x = exp2_raw(a.x);
                e.y = exp2_raw(a.y);
                v2f sg;
                sg.x = fast_rcp(e.x + 1.0f);
                sg.y = fast_rcp(e.y + 1.0f);
                // wsc*tanh(a_nat) = wsc - 2*wsc*sigma, folded into C2/w2
                sc = sc + v2splat(w2[kk]) * sg;
            }
            v2f p;
            p.x = exp2_raw(sc.x);                   // bounded |sc| -> no max-sub
            p.y = exp2_raw(sc.y);
            rv[h] = rv[h] + p;
            rv[NH+h*KD+0] = rv[NH+h*KD+0] + p * f0;
            rv[NH+h*KD+1] = rv[NH+h*KD+1] + p * f1;
            rv[NH+h*KD+2] = rv[NH+h*KD+2] + p * f2;
            rv[NH+h*KD+3] = rv[NH+h*KD+3] + p * f3;
            rv[NH+h*KD+4] = rv[NH+h*KD+4] + p * f4;
        }
    }

    // ---- fold v2 accumulators, single-wave reduction + broadcast
    float red[NR];
    #pragma unroll
    for (int n = 0; n < NR; n++) red[n] = rv[n].x + rv[n].y;
    #pragma unroll
    for (int n = 0; n < NR; n++) red[n] = wave_sum63(red[n]);
    float fin[NR];
    #pragma unroll
    for (int n = 0; n < NR; n++) fin[n] = bcast(red[n], 63);

    // ---- Wv projection (deferred, linear) + softmax normalize (lanes 0..14)
    // fin's value part carries factor K2E -> un-scale by INVK
    float xm = 0.0f;
    if (lane < DD) {
        const int h = lane / KD;
        float acc = 0.0f;
        #pragma unroll
        for (int c = 0; c < KD; c++) acc = fmaf(Wv[lane*KD+c], fin[NH+h*KD+c], acc);
        xm = acc * fast_rcp(fin[h]) * INVK;
    }

    // ---- LN1 across lanes 0..15 (lane 15 contributes 0)
    float s1 = xm, sq = xm*xm;
    #pragma unroll
    for (int off = 8; off >= 1; off >>= 1) {
        s1 += __shfl_xor(s1, off, 16);
        sq += __shfl_xor(sq, off, 16);
    }
    const float mu1   = s1 * (1.0f/DD);
    const float rstd1 = rsqrtf(sq * (1.0f/DD) - mu1*mu1 + 1e-5f);
    float xln = 0.0f;
    if (lane < DD) xln = (xm - mu1) * rstd1 * g1[lane] + beta1[lane];

    // broadcast LN1 output for the MLP
    float xs[DD];
    #pragma unroll
    for (int d = 0; d < DD; d++) xs[d] = bcast(xln, d);

    // ---- MLP layer 1: 75 hidden units over 64 lanes (lanes 0..10 do two)
    {
        float h0 = bff1[lane];
        #pragma unroll
        for (int k = 0; k < DD; k++) h0 = fmaf(W1[lane*DD+k], xs[k], h0);
        s_h[wv][lane] = fmaxf(h0, 0.0f);
        if (lane < HID-64) {
            float h1 = bff1[lane+64];
            #pragma unroll
            for (int k = 0; k < DD; k++) h1 = fmaf(W1[(lane+64)*DD+k], xs[k], h1);
            s_h[wv][lane+64] = fmaxf(h1, 0.0f);
        }
    }
    // same-wave LDS producer/consumer: compiler inserts lgkmcnt wait

    // ---- MLP layer 2: 3 chunks x 25 over lane groups, combine via shfl
    const int c2  = lane >> 4;               // 0..3
    const int d2c = lane & 15;
    const int cc  = (c2 < 3) ? c2 : 2;       // clamp for safe addressing
    const int dc  = (d2c < DD) ? d2c : 0;
    float acc2 = 0.0f;
    #pragma unroll
    for (int k = 0; k < 25; k++)
        acc2 = fmaf(W2[dc*HID + cc*25 + k], s_h[wv][cc*25 + k], acc2);
    acc2 = (c2 < 3) ? acc2 : 0.0f;           // kill duplicated chunk
    acc2 += __shfl_xor(acc2, 16);
    acc2 += __shfl_xor(acc2, 32);            // lanes 0..15 hold full sums

    // ---- residual + LN2 + store
    float x2 = 0.0f;
    if (lane < DD) x2 = xln + bff2[lane] + acc2;   // residual uses post-LN1 x
    float t1 = x2, t2 = x2*x2;
    #pragma unroll
    for (int off = 8; off >= 1; off >>= 1) {
        t1 += __shfl_xor(t1, off, 16);
        t2 += __shfl_xor(t2, off, 16);
    }
    const float mu2   = t1 * (1.0f/DD);
    const float rstd2 = rsqrtf(t2 * (1.0f/DD) - mu2*mu2 + 1e-5f);
    if (lane < DD)
        out[(size_t)qgrp*DD + lane] = (x2 - mu2) * rstd2 * g2[lane] + beta2[lane];
}

extern "C" void kernel_launch(void* const* d_in, const int* in_sizes, int n_in,
                              void* d_out, int out_size, void* d_ws, size_t ws_size,
                              hipStream_t stream) {
    const float* state    = (const float*)d_in[0];
    const float* action   = (const float*)d_in[1];
    const float* Wk       = (const float*)d_in[2];
    const float* Wq       = (const float*)d_in[3];
    const float* Wv       = (const float*)d_in[4];
    const float* att_bias = (const float*)d_in[5];
    const float* Wscore   = (const float*)d_in[6];
    const float* bscore   = (const float*)d_in[7];
    const float* g1       = (const float*)d_in[8];
    const float* beta1    = (const float*)d_in[9];
    const float* W1       = (const float*)d_in[10];
    const float* bff1     = (const float*)d_in[11];
    const float* W2       = (const float*)d_in[12];
    const float* bff2     = (const float*)d_in[13];
    const float* g2       = (const float*)d_in[14];
    const float* beta2    = (const float*)d_in[15];
    float* out = (float*)d_out;

    dim3 grid(32 * 256 / 4);   // 4 queries (waves) per block
    dim3 block(256);
    fused_block_kernel<<<grid, block, 0, stream>>>(
        state, action, Wk, Wq, Wv, att_bias, Wscore, bscore,
        g1, beta1, W1, bff1, W2, bff2, g2, beta2, out);
}